// Round 1
// baseline (2330.860 us; speedup 1.0000x reference)
//
#include <hip/hip_runtime.h>
#include <cstddef>
#include <cstdint>

#define HEADS 8
#define DH 64
#define C 512
#define TC 1536
#define BT 32
#define NTOK 2304
#define TT 16
#define EPS 1e-6f

// elu(x)+1 : x>0 -> x+1 ; else exp(x)
__device__ __forceinline__ float fmap(float x) {
    return x > 0.f ? x + 1.f : __expf(x);
}

// ---------------------------------------------------------------------------
// K1: partial sums for x_time (raw, per channel) and motion mean (raw).
// grid (BT, 8 splits), block 256. Accumulate via atomicAdd into zeroed ws.
// ---------------------------------------------------------------------------
__global__ __launch_bounds__(256) void k_time_reduce(
    const float* __restrict__ x, const float* __restrict__ motion,
    float* __restrict__ xtraw, float* __restrict__ mmraw) {
    int bt = blockIdx.x, sp = blockIdx.y, tid = threadIdx.x;
    int n0 = sp * 288;
    const float* xp = x + ((size_t)bt * NTOK + n0) * C;
    float a0 = 0.f, a1 = 0.f;
    for (int n = 0; n < 288; ++n) {
        a0 += xp[(size_t)n * C + tid];
        a1 += xp[(size_t)n * C + tid + 256];
    }
    atomicAdd(&xtraw[bt * C + tid], a0);
    atomicAdd(&xtraw[bt * C + tid + 256], a1);

    const float* mp = motion + (size_t)bt * NTOK + n0;
    float m = mp[tid];
    if (tid < 32) m += mp[256 + tid];
    __shared__ float red[256];
    red[tid] = m;
    __syncthreads();
    for (int s = 128; s > 0; s >>= 1) {
        if (tid < s) red[tid] += red[tid + s];
        __syncthreads();
    }
    if (tid == 0) atomicAdd(&mmraw[bt], red[0]);
}

// ---------------------------------------------------------------------------
// K2a: qkv_time[bt][0:1536] = x_time[bt] @ W_qkv.  grid BT, block 256.
// x_time = xtraw/2304 + temporal_emb.
// ---------------------------------------------------------------------------
__global__ __launch_bounds__(256) void k_time_qkv(
    const float* __restrict__ xtraw, const float* __restrict__ temb,
    const float* __restrict__ W, float* __restrict__ qkvt) {
    int bt = blockIdx.x, tid = threadIdx.x;
    __shared__ float xl[C];
    xl[tid]       = xtraw[bt * C + tid]       * (1.f / NTOK) + temb[tid];
    xl[tid + 256] = xtraw[bt * C + tid + 256] * (1.f / NTOK) + temb[tid + 256];
    __syncthreads();
    float acc[6] = {0.f, 0.f, 0.f, 0.f, 0.f, 0.f};
    for (int c = 0; c < C; ++c) {
        float xv = xl[c];
        const float* wr = W + (size_t)c * TC + tid;
#pragma unroll
        for (int i = 0; i < 6; ++i) acc[i] += xv * wr[i * 256];
    }
#pragma unroll
    for (int i = 0; i < 6; ++i) qkvt[(size_t)bt * TC + tid + i * 256] = acc[i];
}

// ---------------------------------------------------------------------------
// K2b: temporal linear attention -> bias[bt][c] = temporal_emb[c] + t_out.
// grid (B=2, HEADS), block 256.
// ---------------------------------------------------------------------------
__global__ __launch_bounds__(256) void k_time_attn(
    const float* __restrict__ qkvt, const float* __restrict__ mmraw,
    const float* __restrict__ temb, float* __restrict__ bias) {
    int b = blockIdx.x, h = blockIdx.y, tid = threadIdx.x;
    int d = tid & 63, g = tid >> 6;  // g in [0,4)
    __shared__ float qs[TT][DH], ks[TT][DH], vs[TT][DH], ksum[DH];
    __shared__ float kvl[DH][DH];
    for (int t = g; t < TT; t += 4) {
        size_t base = (size_t)(b * TT + t) * TC + h * DH + d;
        float mwt = 1.f + tanhf(mmraw[b * TT + t] * (1.f / NTOK));
        qs[t][d] = fmap(qkvt[base]) * mwt;
        ks[t][d] = fmap(qkvt[base + C]);
        vs[t][d] = qkvt[base + 2 * C];
    }
    __syncthreads();
    if (g == 0) {
        float s = 0.f;
        for (int t = 0; t < TT; ++t) s += ks[t][d];
        ksum[d] = s;
    }
    float kva[16];
#pragma unroll
    for (int i = 0; i < 16; ++i) kva[i] = 0.f;
    for (int t = 0; t < TT; ++t) {
        float kd = ks[t][d];
#pragma unroll
        for (int i = 0; i < 16; ++i) kva[i] += kd * vs[t][g * 16 + i];
    }
#pragma unroll
    for (int i = 0; i < 16; ++i) kvl[d][g * 16 + i] = kva[i];
    __syncthreads();
    for (int tt = 0; tt < 4; ++tt) {
        int t = g * 4 + tt;
        float acc = 0.f, zden = 0.f;
        for (int dd = 0; dd < DH; ++dd) {
            float qv = qs[t][dd];
            acc  += qv * kvl[dd][d];
            zden += qv * ksum[dd];
        }
        float outv = acc / (zden + EPS);
        bias[(size_t)(b * TT + t) * C + h * DH + d] = outv + temb[h * DH + d];
    }
}

// ---------------------------------------------------------------------------
// K3: spatial pass A. Per (bt, h, split): compute k,v = fmap-side of
// (x+bias) @ W for 576 tokens, accumulate kv[64][64] and ksum[64],
// atomicAdd into ws. Tiled GEMM: M=32 tokens, N=128 cols (k|v), Kc=32.
// ---------------------------------------------------------------------------
__global__ __launch_bounds__(256) void k_spatial_kv(
    const float* __restrict__ x, const float* __restrict__ W,
    const float* __restrict__ bias, float* __restrict__ kvw,
    float* __restrict__ ksw) {
    int bt = blockIdx.x, h = blockIdx.y, s = blockIdx.z, tid = threadIdx.x;
    __shared__ __align__(16) float biasl[C];
    __shared__ __align__(16) float xT[32][36];     // [k][token], padded
    __shared__ __align__(16) float Ws[32 * 128];   // [k][col]
    __shared__ __align__(16) float kvs[32 * 132];  // [token][col], padded
    biasl[tid]       = bias[(size_t)bt * C + tid];
    biasl[tid + 256] = bias[(size_t)bt * C + tid + 256];

    float kvacc[16];
#pragma unroll
    for (int i = 0; i < 16; ++i) kvacc[i] = 0.f;
    float ksacc = 0.f;

    const int colK = C + h * DH, colV = 2 * C + h * DH;
    const int tg = tid >> 5, cg = tid & 31;   // GEMM: 4 tokens x 4 cols
    const int dr = tid >> 4, ec = tid & 15;   // kv-accum: 4 d x 4 e
    const int n_l = tid >> 3, k0 = (tid & 7) * 4;  // xT staging
    const int wj = tid & 127, wk0 = tid >> 7;      // Ws staging

    for (int tile = 0; tile < 18; ++tile) {
        int n0 = s * 576 + tile * 32;
        float acc[16];
#pragma unroll
        for (int i = 0; i < 16; ++i) acc[i] = 0.f;

        for (int kc = 0; kc < 16; ++kc) {
            __syncthreads();
            {
                const float4 xv4 = *(const float4*)(
                    x + ((size_t)(bt * NTOK + n0 + n_l)) * C + kc * 32 + k0);
                int c = kc * 32 + k0;
                xT[k0 + 0][n_l] = xv4.x + biasl[c + 0];
                xT[k0 + 1][n_l] = xv4.y + biasl[c + 1];
                xT[k0 + 2][n_l] = xv4.z + biasl[c + 2];
                xT[k0 + 3][n_l] = xv4.w + biasl[c + 3];
            }
#pragma unroll
            for (int r = 0; r < 16; ++r) {
                int k = r * 2 + wk0;
                int col = (wj < 64) ? (colK + wj) : (colV + wj - 64);
                Ws[k * 128 + wj] = W[(size_t)(kc * 32 + k) * TC + col];
            }
            __syncthreads();
#pragma unroll
            for (int k = 0; k < 32; ++k) {
                float4 xv = *(const float4*)&xT[k][tg * 4];
                float4 wv = *(const float4*)&Ws[k * 128 + cg * 4];
                float xa[4] = {xv.x, xv.y, xv.z, xv.w};
                float wa[4] = {wv.x, wv.y, wv.z, wv.w};
#pragma unroll
                for (int i = 0; i < 4; ++i)
#pragma unroll
                    for (int j = 0; j < 4; ++j) acc[i * 4 + j] += xa[i] * wa[j];
            }
        }
        // epilogue: feature-map k columns, stash k|v tile, accumulate kv.
#pragma unroll
        for (int i = 0; i < 4; ++i)
#pragma unroll
            for (int j = 0; j < 4; ++j) {
                int jj = cg * 4 + j;
                float v = acc[i * 4 + j];
                if (jj < DH) v = fmap(v);
                kvs[(tg * 4 + i) * 132 + jj] = v;
            }
        __syncthreads();
#pragma unroll 4
        for (int n = 0; n < 32; ++n) {
            float4 kd = *(const float4*)&kvs[n * 132 + dr * 4];
            float4 ve = *(const float4*)&kvs[n * 132 + 64 + ec * 4];
            float ka[4] = {kd.x, kd.y, kd.z, kd.w};
            float va[4] = {ve.x, ve.y, ve.z, ve.w};
#pragma unroll
            for (int i = 0; i < 4; ++i)
#pragma unroll
                for (int j = 0; j < 4; ++j) kvacc[i * 4 + j] += ka[i] * va[j];
        }
        if (tid < 64) {
            float ss = 0.f;
#pragma unroll 4
            for (int n = 0; n < 32; ++n) ss += kvs[n * 132 + tid];
            ksacc += ss;
        }
    }
    float* kvp = kvw + (size_t)(bt * HEADS + h) * DH * DH;
#pragma unroll
    for (int i = 0; i < 4; ++i)
#pragma unroll
        for (int j = 0; j < 4; ++j)
            atomicAdd(&kvp[(dr * 4 + i) * DH + ec * 4 + j], kvacc[i * 4 + j]);
    if (tid < 64) atomicAdd(&ksw[(bt * HEADS + h) * DH + tid], ksacc);
}

// ---------------------------------------------------------------------------
// K4: spatial pass B. Per (bt, h, split): q = fmap((x+bias)@W_q)*mw,
// out = (q @ kv) / (q . ksum + eps). Tiled GEMM: M=64 tokens, N=64, Kc=32.
// ---------------------------------------------------------------------------
__global__ __launch_bounds__(256) void k_spatial_out(
    const float* __restrict__ x, const float* __restrict__ W,
    const float* __restrict__ bias, const float* __restrict__ motion,
    const float* __restrict__ kvw, const float* __restrict__ ksw,
    float* __restrict__ out) {
    int bt = blockIdx.x, h = blockIdx.y, s = blockIdx.z, tid = threadIdx.x;
    __shared__ __align__(16) float biasl[C];
    __shared__ __align__(16) float xT[32][68];    // [k][token], padded
    __shared__ __align__(16) float Ws[32 * 64];   // [k][col]
    __shared__ __align__(16) float qsT[64][68];   // [d][token], padded
    __shared__ __align__(16) float kvl[DH * DH];
    __shared__ float ksl[DH], mwv[64], zv[64];
    biasl[tid]       = bias[(size_t)bt * C + tid];
    biasl[tid + 256] = bias[(size_t)bt * C + tid + 256];
    {
        const float* kvp = kvw + (size_t)(bt * HEADS + h) * DH * DH;
#pragma unroll
        for (int i = 0; i < 16; ++i) kvl[tid + i * 256] = kvp[tid + i * 256];
    }
    if (tid < 64) ksl[tid] = ksw[(bt * HEADS + h) * DH + tid];

    const int colQ = h * DH;
    const int tg = tid >> 4, cg = tid & 15;        // GEMM: 4 tokens x 4 cols
    const int n_l = tid >> 2, k0 = (tid & 3) * 8;  // xT staging
    const int wj = tid & 63, wk0 = tid >> 6;       // Ws staging

    for (int tile = 0; tile < 9; ++tile) {
        int n0 = s * 576 + tile * 64;
        float acc[16];
#pragma unroll
        for (int i = 0; i < 16; ++i) acc[i] = 0.f;

        for (int kc = 0; kc < 16; ++kc) {
            __syncthreads();
            {
                const float* xp =
                    x + ((size_t)(bt * NTOK + n0 + n_l)) * C + kc * 32 + k0;
                float4 a = *(const float4*)xp;
                float4 b4 = *(const float4*)(xp + 4);
                int c = kc * 32 + k0;
                xT[k0 + 0][n_l] = a.x + biasl[c + 0];
                xT[k0 + 1][n_l] = a.y + biasl[c + 1];
                xT[k0 + 2][n_l] = a.z + biasl[c + 2];
                xT[k0 + 3][n_l] = a.w + biasl[c + 3];
                xT[k0 + 4][n_l] = b4.x + biasl[c + 4];
                xT[k0 + 5][n_l] = b4.y + biasl[c + 5];
                xT[k0 + 6][n_l] = b4.z + biasl[c + 6];
                xT[k0 + 7][n_l] = b4.w + biasl[c + 7];
            }
#pragma unroll
            for (int r = 0; r < 8; ++r) {
                int k = r * 4 + wk0;
                Ws[k * 64 + wj] = W[(size_t)(kc * 32 + k) * TC + colQ + wj];
            }
            if (kc == 0 && tid < 64)
                mwv[tid] = 1.f + tanhf(motion[(size_t)bt * NTOK + n0 + tid]);
            __syncthreads();
#pragma unroll
            for (int k = 0; k < 32; ++k) {
                float4 xv = *(const float4*)&xT[k][tg * 4];
                float4 wv = *(const float4*)&Ws[k * 64 + cg * 4];
                float xa[4] = {xv.x, xv.y, xv.z, xv.w};
                float wa[4] = {wv.x, wv.y, wv.z, wv.w};
#pragma unroll
                for (int i = 0; i < 4; ++i)
#pragma unroll
                    for (int j = 0; j < 4; ++j) acc[i * 4 + j] += xa[i] * wa[j];
            }
        }
        // epilogue: q' = fmap(q)*mw, transpose to LDS, z per token, out.
#pragma unroll
        for (int i = 0; i < 4; ++i)
#pragma unroll
            for (int j = 0; j < 4; ++j) {
                int nn = tg * 4 + i, dd = cg * 4 + j;
                qsT[dd][nn] = fmap(acc[i * 4 + j]) * mwv[nn];
            }
        __syncthreads();
        if (tid < 64) {
            float zd = 0.f;
#pragma unroll 8
            for (int dd = 0; dd < DH; ++dd) zd += qsT[dd][tid] * ksl[dd];
            zv[tid] = 1.f / (zd + EPS);
        }
        __syncthreads();
        float o[16];
#pragma unroll
        for (int i = 0; i < 16; ++i) o[i] = 0.f;
#pragma unroll 4
        for (int dd = 0; dd < DH; ++dd) {
            float4 qv = *(const float4*)&qsT[dd][tg * 4];
            float4 kvv = *(const float4*)&kvl[dd * DH + cg * 4];
            float qa[4] = {qv.x, qv.y, qv.z, qv.w};
            float ca[4] = {kvv.x, kvv.y, kvv.z, kvv.w};
#pragma unroll
            for (int i = 0; i < 4; ++i)
#pragma unroll
                for (int j = 0; j < 4; ++j) o[i * 4 + j] += qa[i] * ca[j];
        }
        float* op = out + ((size_t)(bt * NTOK + n0)) * C + colQ + cg * 4;
#pragma unroll
        for (int i = 0; i < 4; ++i) {
            int nn = tg * 4 + i;
            float z = zv[nn];
            float4 w4 = make_float4(o[i * 4 + 0] * z, o[i * 4 + 1] * z,
                                    o[i * 4 + 2] * z, o[i * 4 + 3] * z);
            *(float4*)(op + (size_t)nn * C) = w4;
        }
    }
}

// ---------------------------------------------------------------------------
extern "C" void kernel_launch(void* const* d_in, const int* in_sizes, int n_in,
                              void* d_out, int out_size, void* d_ws, size_t ws_size,
                              hipStream_t stream) {
    (void)in_sizes; (void)n_in; (void)out_size; (void)ws_size;
    const float* x      = (const float*)d_in[0];
    const float* motion = (const float*)d_in[1];
    const float* W      = (const float*)d_in[2];
    const float* temb   = (const float*)d_in[3];
    float* out = (float*)d_out;
    float* ws  = (float*)d_ws;

    // ws layout (floats)
    float* kvw   = ws;                 // 32*8*64*64 = 1048576
    float* ksw   = kvw + 1048576;      // 32*8*64    = 16384
    float* xtraw = ksw + 16384;        // 32*512     = 16384
    float* mmraw = xtraw + 16384;      // 32
    float* qkvt  = mmraw + 32;         // 32*1536    = 49152
    float* bias  = qkvt + 49152;       // 32*512     = 16384

    hipMemsetAsync(d_ws, 0, (size_t)(1048576 + 16384 + 16384 + 32) * sizeof(float),
                   stream);
    k_time_reduce<<<dim3(BT, 8), 256, 0, stream>>>(x, motion, xtraw, mmraw);
    k_time_qkv<<<dim3(BT), 256, 0, stream>>>(xtraw, temb, W, qkvt);
    k_time_attn<<<dim3(2, HEADS), 256, 0, stream>>>(qkvt, mmraw, temb, bias);
    k_spatial_kv<<<dim3(BT, HEADS, 4), 256, 0, stream>>>(x, W, bias, kvw, ksw);
    k_spatial_out<<<dim3(BT, HEADS, 4), 256, 0, stream>>>(x, W, bias, motion, kvw,
                                                          ksw, out);
}

// Round 2
// 681.476 us; speedup vs baseline: 3.4203x; 3.4203x over previous
//
#include <hip/hip_runtime.h>
#include <cstddef>
#include <cstdint>

#define HEADS 8
#define DH 64
#define C 512
#define TC 1536
#define BT 32
#define NTOK 2304
#define TT 16
#define EPS 1e-6f

typedef __attribute__((ext_vector_type(8))) short bf16x8;
typedef __attribute__((ext_vector_type(4))) float f32x4;

__device__ __forceinline__ float fmap(float x) {
    return x > 0.f ? x + 1.f : __expf(x);
}
__device__ __forceinline__ unsigned short f2bf(float f) {
    unsigned int u = __float_as_uint(f);
    return (unsigned short)((u + 0x7fffu + ((u >> 16) & 1u)) >> 16);
}
__device__ __forceinline__ unsigned int pack2bf(float a, float b) {
    return (unsigned int)f2bf(a) | ((unsigned int)f2bf(b) << 16);
}
__device__ __forceinline__ float bf2f(unsigned short h) {
    return __uint_as_float(((unsigned int)h) << 16);
}

// ---------------------------------------------------------------------------
// K0: Wt[col][c] (bf16, col=0..1535, c=0..511) = W[c][col]. grid (48,16).
// ---------------------------------------------------------------------------
__global__ __launch_bounds__(256) void k_prep_w(
    const float* __restrict__ W, unsigned short* __restrict__ Wt) {
    __shared__ float tile[32][33];
    int col0 = blockIdx.x * 32, c0 = blockIdx.y * 32;
    int tx = threadIdx.x & 31, ty = threadIdx.x >> 5;  // 32 x 8
#pragma unroll
    for (int j = 0; j < 4; ++j) {
        int c = ty + j * 8;
        tile[c][tx] = W[(size_t)(c0 + c) * TC + col0 + tx];
    }
    __syncthreads();
#pragma unroll
    for (int j = 0; j < 4; ++j) {
        int col = ty + j * 8;
        Wt[(size_t)(col0 + col) * C + c0 + tx] = f2bf(tile[tx][col]);
    }
}

// ---------------------------------------------------------------------------
// K1: partial sums for x_time (per channel) and motion mean (raw sums).
// ---------------------------------------------------------------------------
__global__ __launch_bounds__(256) void k_time_reduce(
    const float* __restrict__ x, const float* __restrict__ motion,
    float* __restrict__ xtraw, float* __restrict__ mmraw) {
    int bt = blockIdx.x, sp = blockIdx.y, tid = threadIdx.x;
    int n0 = sp * 288;
    const float* xp = x + ((size_t)bt * NTOK + n0) * C;
    float a0 = 0.f, a1 = 0.f;
    for (int n = 0; n < 288; ++n) {
        a0 += xp[(size_t)n * C + tid];
        a1 += xp[(size_t)n * C + tid + 256];
    }
    atomicAdd(&xtraw[bt * C + tid], a0);
    atomicAdd(&xtraw[bt * C + tid + 256], a1);

    const float* mp = motion + (size_t)bt * NTOK + n0;
    float m = mp[tid];
    if (tid < 32) m += mp[256 + tid];
    __shared__ float red[256];
    red[tid] = m;
    __syncthreads();
    for (int s = 128; s > 0; s >>= 1) {
        if (tid < s) red[tid] += red[tid + s];
        __syncthreads();
    }
    if (tid == 0) atomicAdd(&mmraw[bt], red[0]);
}

// ---------------------------------------------------------------------------
// K2a: qkv_time[bt][0:1536] = x_time[bt] @ W_qkv.
// ---------------------------------------------------------------------------
__global__ __launch_bounds__(256) void k_time_qkv(
    const float* __restrict__ xtraw, const float* __restrict__ temb,
    const float* __restrict__ W, float* __restrict__ qkvt) {
    int bt = blockIdx.x, tid = threadIdx.x;
    __shared__ float xl[C];
    xl[tid]       = xtraw[bt * C + tid]       * (1.f / NTOK) + temb[tid];
    xl[tid + 256] = xtraw[bt * C + tid + 256] * (1.f / NTOK) + temb[tid + 256];
    __syncthreads();
    float acc[6] = {0.f, 0.f, 0.f, 0.f, 0.f, 0.f};
    for (int c = 0; c < C; ++c) {
        float xv = xl[c];
        const float* wr = W + (size_t)c * TC + tid;
#pragma unroll
        for (int i = 0; i < 6; ++i) acc[i] += xv * wr[i * 256];
    }
#pragma unroll
    for (int i = 0; i < 6; ++i) qkvt[(size_t)bt * TC + tid + i * 256] = acc[i];
}

// ---------------------------------------------------------------------------
// K2b: temporal linear attention -> bias[bt][c] = temporal_emb[c] + t_out.
// ---------------------------------------------------------------------------
__global__ __launch_bounds__(256) void k_time_attn(
    const float* __restrict__ qkvt, const float* __restrict__ mmraw,
    const float* __restrict__ temb, float* __restrict__ bias) {
    int b = blockIdx.x, h = blockIdx.y, tid = threadIdx.x;
    int d = tid & 63, g = tid >> 6;
    __shared__ float qs[TT][DH], ks[TT][DH], vs[TT][DH], ksum[DH];
    __shared__ float kvl[DH][DH];
    for (int t = g; t < TT; t += 4) {
        size_t base = (size_t)(b * TT + t) * TC + h * DH + d;
        float mwt = 1.f + tanhf(mmraw[b * TT + t] * (1.f / NTOK));
        qs[t][d] = fmap(qkvt[base]) * mwt;
        ks[t][d] = fmap(qkvt[base + C]);
        vs[t][d] = qkvt[base + 2 * C];
    }
    __syncthreads();
    if (g == 0) {
        float s = 0.f;
        for (int t = 0; t < TT; ++t) s += ks[t][d];
        ksum[d] = s;
    }
    float kva[16];
#pragma unroll
    for (int i = 0; i < 16; ++i) kva[i] = 0.f;
    for (int t = 0; t < TT; ++t) {
        float kd = ks[t][d];
#pragma unroll
        for (int i = 0; i < 16; ++i) kva[i] += kd * vs[t][g * 16 + i];
    }
#pragma unroll
    for (int i = 0; i < 16; ++i) kvl[d][g * 16 + i] = kva[i];
    __syncthreads();
    for (int tt = 0; tt < 4; ++tt) {
        int t = g * 4 + tt;
        float acc = 0.f, zden = 0.f;
        for (int dd = 0; dd < DH; ++dd) {
            float qv = qs[t][dd];
            acc  += qv * kvl[dd][d];
            zden += qv * ksum[dd];
        }
        bias[(size_t)(b * TT + t) * C + h * DH + d] =
            acc / (zden + EPS) + temb[h * DH + d];
    }
}

// ---------------------------------------------------------------------------
// K3: spatial pass A (MFMA). grid (3, HEADS, BT); 6 tiles of 128 tokens each.
// GEMM (x+bias)@W[k|v] 128x128, then kv/ksum accumulation via MFMA.
// ---------------------------------------------------------------------------
__global__ __launch_bounds__(256, 3) void k_spatial_kv(
    const float* __restrict__ x, const unsigned short* __restrict__ Wt,
    const float* __restrict__ bias, float* __restrict__ kvw,
    float* __restrict__ ksw) {
    __shared__ __align__(16) char smem[39936];
    unsigned short* A_s = (unsigned short*)smem;            // [128][72]
    unsigned short* B_s = (unsigned short*)(smem + 18432);  // [128][72]
    unsigned short* kvT = (unsigned short*)smem;            // [128][136] alias
    float* biasl = (float*)(smem + 36864);                  // [512]
    float* red   = (float*)(smem + 38912);                  // [256]

    const int s = blockIdx.x, h = blockIdx.y, bt = blockIdx.z;
    const int tid = threadIdx.x, lane = tid & 63, wave = tid >> 6;
    const int lm = lane & 15, quad = lane >> 4;
    const int wm = (wave & 1) * 64, wn = (wave >> 1) * 64;

    biasl[tid]       = bias[bt * C + tid];
    biasl[tid + 256] = bias[bt * C + tid + 256];

    f32x4 kvacc[4];
#pragma unroll
    for (int i = 0; i < 4; ++i) kvacc[i] = (f32x4)0.f;
    float kspart = 0.f;

    const int arow = tid >> 3, acid = tid & 7;   // A staging: 32 rows x 8 chunks
    const int bcol = tid >> 1, bpart = tid & 1;  // B staging: 128 cols x 2
    const int wtrow = (bcol < 64) ? (C + h * DH + bcol) : (2 * C + h * DH + bcol - 64);
    const unsigned short* WtB = Wt + (size_t)wtrow * C;

    for (int tile = 0; tile < 6; ++tile) {
        const int n0 = (s * 6 + tile) * 128;
        f32x4 acc[4][4];
#pragma unroll
        for (int i = 0; i < 4; ++i)
#pragma unroll
            for (int j = 0; j < 4; ++j) acc[i][j] = (f32x4)0.f;

        for (int kc = 0; kc < 8; ++kc) {
            __syncthreads();
            // stage A (x + bias -> bf16), 4 rows of 8 floats per thread
#pragma unroll
            for (int j = 0; j < 4; ++j) {
                int row = arow + 32 * j;
                const float* xp = x + ((size_t)(bt * NTOK + n0 + row)) * C +
                                  kc * 64 + acid * 8;
                float4 u = *(const float4*)xp;
                float4 v = *(const float4*)(xp + 4);
                const float* bl = biasl + kc * 64 + acid * 8;
                uint4 pk;
                pk.x = pack2bf(u.x + bl[0], u.y + bl[1]);
                pk.y = pack2bf(u.z + bl[2], u.w + bl[3]);
                pk.z = pack2bf(v.x + bl[4], v.y + bl[5]);
                pk.w = pack2bf(v.z + bl[6], v.w + bl[7]);
                *(uint4*)&A_s[row * 72 + acid * 8] = pk;
            }
            // stage B (Wt already bf16): 32 ushorts per thread
            {
                const unsigned short* wp = WtB + kc * 64 + bpart * 32;
                uint4 w0 = ((const uint4*)wp)[0];
                uint4 w1 = ((const uint4*)wp)[1];
                uint4 w2 = ((const uint4*)wp)[2];
                uint4 w3 = ((const uint4*)wp)[3];
                uint4* dst = (uint4*)&B_s[bcol * 72 + bpart * 32];
                dst[0] = w0; dst[1] = w1; dst[2] = w2; dst[3] = w3;
            }
            __syncthreads();
#pragma unroll
            for (int ks = 0; ks < 2; ++ks) {
                bf16x8 af[4], bf[4];
#pragma unroll
                for (int i = 0; i < 4; ++i)
                    af[i] = *(const bf16x8*)&A_s[(wm + i * 16 + lm) * 72 +
                                                 ks * 32 + quad * 8];
#pragma unroll
                for (int j = 0; j < 4; ++j)
                    bf[j] = *(const bf16x8*)&B_s[(wn + j * 16 + lm) * 72 +
                                                 ks * 32 + quad * 8];
#pragma unroll
                for (int i = 0; i < 4; ++i)
#pragma unroll
                    for (int j = 0; j < 4; ++j)
                        acc[i][j] = __builtin_amdgcn_mfma_f32_16x16x32_bf16(
                            af[i], bf[j], acc[i][j], 0, 0, 0);
            }
        }
        __syncthreads();
        // write k^T|v^T tile (bf16) over A_s/B_s: kvT[col][token]
#pragma unroll
        for (int i = 0; i < 4; ++i)
#pragma unroll
            for (int j = 0; j < 4; ++j) {
                int col = wn + j * 16 + lm;
                int tok = wm + i * 16 + quad * 4;
                f32x4 a4 = acc[i][j];
                float v0 = a4[0], v1 = a4[1], v2 = a4[2], v3 = a4[3];
                if (wn == 0) {  // k columns: apply feature map
                    v0 = fmap(v0); v1 = fmap(v1); v2 = fmap(v2); v3 = fmap(v3);
                }
                uint2 pk;
                pk.x = pack2bf(v0, v1);
                pk.y = pack2bf(v2, v3);
                *(uint2*)&kvT[col * 136 + tok] = pk;
            }
        __syncthreads();
        // ksum partials
        {
            int d = tid & 63, g2 = tid >> 6;
            const unsigned short* kr = &kvT[d * 136 + g2 * 32];
            float ssum = 0.f;
#pragma unroll 8
            for (int j = 0; j < 32; ++j) ssum += bf2f(kr[j]);
            kspart += ssum;
        }
        // kv += k^T @ v via MFMA; wave handles e-tile = wave*16
#pragma unroll
        for (int ks2 = 0; ks2 < 4; ++ks2) {
            bf16x8 bfv = *(const bf16x8*)&kvT[(64 + wave * 16 + lm) * 136 +
                                             ks2 * 32 + quad * 8];
#pragma unroll
            for (int i = 0; i < 4; ++i) {
                bf16x8 afk = *(const bf16x8*)&kvT[(i * 16 + lm) * 136 +
                                                  ks2 * 32 + quad * 8];
                kvacc[i] = __builtin_amdgcn_mfma_f32_16x16x32_bf16(
                    afk, bfv, kvacc[i], 0, 0, 0);
            }
        }
    }
    float* kvp = kvw + (size_t)(bt * HEADS + h) * DH * DH;
#pragma unroll
    for (int i = 0; i < 4; ++i)
#pragma unroll
        for (int r = 0; r < 4; ++r) {
            int d = i * 16 + quad * 4 + r, e = wave * 16 + lm;
            atomicAdd(&kvp[d * DH + e], kvacc[i][r]);
        }
    red[tid] = kspart;
    __syncthreads();
    if (tid < 64) {
        float kss = red[tid] + red[tid + 64] + red[tid + 128] + red[tid + 192];
        atomicAdd(&ksw[(bt * HEADS + h) * DH + tid], kss);
    }
}

// ---------------------------------------------------------------------------
// K4: spatial pass B (MFMA). grid (9, HEADS, BT); one 256-token tile/block.
// q = fmap((x+bias)@Wq)*mw ; out = (q@kv) / (q.ksum + eps).
// ---------------------------------------------------------------------------
__global__ __launch_bounds__(256, 3) void k_spatial_out(
    const float* __restrict__ x, const unsigned short* __restrict__ Wt,
    const float* __restrict__ bias, const float* __restrict__ motion,
    const float* __restrict__ kvw, const float* __restrict__ ksw,
    float* __restrict__ out) {
    __shared__ __align__(16) char smem[50432];
    unsigned short* A_s   = (unsigned short*)smem;            // [256][72]
    unsigned short* B_s   = (unsigned short*)(smem + 36864);  // [64][72]
    unsigned short* qs    = (unsigned short*)smem;            // alias A_s
    unsigned short* kvT_s = (unsigned short*)(smem + 36864);  // alias B_s
    float* biasl = (float*)(smem + 46080);  // [512]
    float* ksl   = (float*)(smem + 48128);  // [64]
    float* mwv   = (float*)(smem + 48384);  // [256]
    float* zv    = (float*)(smem + 49408);  // [256]

    const int tile = blockIdx.x, h = blockIdx.y, bt = blockIdx.z;
    const int tid = threadIdx.x, lane = tid & 63, wave = tid >> 6;
    const int lm = lane & 15, quad = lane >> 4;
    const int n0 = tile * 256;

    biasl[tid]       = bias[bt * C + tid];
    biasl[tid + 256] = bias[bt * C + tid + 256];
    mwv[tid] = 1.f + tanhf(motion[(size_t)bt * NTOK + n0 + tid]);
    if (tid < 64) ksl[tid] = ksw[(bt * HEADS + h) * DH + tid];

    const int arow = tid >> 3, acid = tid & 7;   // A staging
    const int bcol = tid >> 2, bpart = tid & 3;  // B staging: 64 cols x 4
    const unsigned short* WtB = Wt + (size_t)(h * DH + bcol) * C;

    f32x4 acc[4][4];
#pragma unroll
    for (int i = 0; i < 4; ++i)
#pragma unroll
        for (int j = 0; j < 4; ++j) acc[i][j] = (f32x4)0.f;

    for (int kc = 0; kc < 8; ++kc) {
        __syncthreads();
#pragma unroll
        for (int j = 0; j < 8; ++j) {
            int row = arow + 32 * j;
            const float* xp = x + ((size_t)(bt * NTOK + n0 + row)) * C +
                              kc * 64 + acid * 8;
            float4 u = *(const float4*)xp;
            float4 v = *(const float4*)(xp + 4);
            const float* bl = biasl + kc * 64 + acid * 8;
            uint4 pk;
            pk.x = pack2bf(u.x + bl[0], u.y + bl[1]);
            pk.y = pack2bf(u.z + bl[2], u.w + bl[3]);
            pk.z = pack2bf(v.x + bl[4], v.y + bl[5]);
            pk.w = pack2bf(v.z + bl[6], v.w + bl[7]);
            *(uint4*)&A_s[row * 72 + acid * 8] = pk;
        }
        {
            const unsigned short* wp = WtB + kc * 64 + bpart * 16;
            uint4 w0 = ((const uint4*)wp)[0];
            uint4 w1 = ((const uint4*)wp)[1];
            uint4* dst = (uint4*)&B_s[bcol * 72 + bpart * 16];
            dst[0] = w0; dst[1] = w1;
        }
        __syncthreads();
#pragma unroll
        for (int ks = 0; ks < 2; ++ks) {
            bf16x8 af[4], bf[4];
#pragma unroll
            for (int i = 0; i < 4; ++i)
                af[i] = *(const bf16x8*)&A_s[(wave * 64 + i * 16 + lm) * 72 +
                                             ks * 32 + quad * 8];
#pragma unroll
            for (int j = 0; j < 4; ++j)
                bf[j] = *(const bf16x8*)&B_s[(j * 16 + lm) * 72 +
                                             ks * 32 + quad * 8];
#pragma unroll
            for (int i = 0; i < 4; ++i)
#pragma unroll
                for (int j = 0; j < 4; ++j)
                    acc[i][j] = __builtin_amdgcn_mfma_f32_16x16x32_bf16(
                        af[i], bf[j], acc[i][j], 0, 0, 0);
        }
    }
    __syncthreads();
    // write q (fmap * mw) as bf16 into qs[token][d]; stage kv^T into kvT_s[e][d]
#pragma unroll
    for (int i = 0; i < 4; ++i)
#pragma unroll
        for (int j = 0; j < 4; ++j) {
            int d = j * 16 + lm;
            int tokb = wave * 64 + i * 16 + quad * 4;
#pragma unroll
            for (int r = 0; r < 4; ++r) {
                float qv = fmap(acc[i][j][r]) * mwv[tokb + r];
                qs[(tokb + r) * 72 + d] = f2bf(qv);
            }
        }
    {
        const float* kvp = kvw + (size_t)(bt * HEADS + h) * DH * DH;
        int d0 = (tid >> 4) * 4, e0 = (tid & 15) * 4;
#pragma unroll
        for (int i = 0; i < 4; ++i) {
            float4 v = *(const float4*)&kvp[(d0 + i) * DH + e0];
            kvT_s[(e0 + 0) * 72 + d0 + i] = f2bf(v.x);
            kvT_s[(e0 + 1) * 72 + d0 + i] = f2bf(v.y);
            kvT_s[(e0 + 2) * 72 + d0 + i] = f2bf(v.z);
            kvT_s[(e0 + 3) * 72 + d0 + i] = f2bf(v.w);
        }
    }
    __syncthreads();
    // z per token
    {
        float zd = 0.f;
        const unsigned short* qr = &qs[tid * 72];
#pragma unroll 8
        for (int d = 0; d < 64; ++d) zd += bf2f(qr[d]) * ksl[d];
        zv[tid] = 1.f / (zd + EPS);
    }
    // out = q @ kv via MFMA
    f32x4 oacc[4][4];
#pragma unroll
    for (int i = 0; i < 4; ++i)
#pragma unroll
        for (int j = 0; j < 4; ++j) oacc[i][j] = (f32x4)0.f;
#pragma unroll
    for (int ks = 0; ks < 2; ++ks) {
        bf16x8 bq[4], bk[4];
#pragma unroll
        for (int i = 0; i < 4; ++i)
            bq[i] = *(const bf16x8*)&qs[(wave * 64 + i * 16 + lm) * 72 +
                                        ks * 32 + quad * 8];
#pragma unroll
        for (int j = 0; j < 4; ++j)
            bk[j] = *(const bf16x8*)&kvT_s[(j * 16 + lm) * 72 +
                                           ks * 32 + quad * 8];
#pragma unroll
        for (int i = 0; i < 4; ++i)
#pragma unroll
            for (int j = 0; j < 4; ++j)
                oacc[i][j] = __builtin_amdgcn_mfma_f32_16x16x32_bf16(
                    bq[i], bk[j], oacc[i][j], 0, 0, 0);
    }
    __syncthreads();  // zv visibility
    float* obase = out + ((size_t)(bt * NTOK + n0)) * C + h * DH;
#pragma unroll
    for (int i = 0; i < 4; ++i)
#pragma unroll
        for (int r = 0; r < 4; ++r) {
            int tok = wave * 64 + i * 16 + quad * 4 + r;
            float z = zv[tok];
#pragma unroll
            for (int j = 0; j < 4; ++j)
                obase[(size_t)tok * C + j * 16 + lm] = oacc[i][j][r] * z;
        }
}

// ---------------------------------------------------------------------------
extern "C" void kernel_launch(void* const* d_in, const int* in_sizes, int n_in,
                              void* d_out, int out_size, void* d_ws, size_t ws_size,
                              hipStream_t stream) {
    (void)in_sizes; (void)n_in; (void)out_size; (void)ws_size;
    const float* x      = (const float*)d_in[0];
    const float* motion = (const float*)d_in[1];
    const float* W      = (const float*)d_in[2];
    const float* temb   = (const float*)d_in[3];
    float* out = (float*)d_out;
    float* ws  = (float*)d_ws;

    // ws layout (floats)
    float* kvw   = ws;                 // 1048576
    float* ksw   = kvw + 1048576;      // 16384
    float* xtraw = ksw + 16384;        // 16384
    float* mmraw = xtraw + 16384;      // 32
    float* qkvt  = mmraw + 32;         // 49152
    float* bias  = qkvt + 49152;       // 16384
    unsigned short* Wt = (unsigned short*)(bias + 16384);  // 1536*512 bf16

    hipMemsetAsync(d_ws, 0, (size_t)(1048576 + 16384 + 16384 + 32) * sizeof(float),
                   stream);
    k_prep_w<<<dim3(48, 16), 256, 0, stream>>>(W, Wt);
    k_time_reduce<<<dim3(BT, 8), 256, 0, stream>>>(x, motion, xtraw, mmraw);
    k_time_qkv<<<dim3(BT), 256, 0, stream>>>(xtraw, temb, W, qkvt);
    k_time_attn<<<dim3(2, HEADS), 256, 0, stream>>>(qkvt, mmraw, temb, bias);
    k_spatial_kv<<<dim3(3, HEADS, BT), 256, 0, stream>>>(x, Wt, bias, kvw, ksw);
    k_spatial_out<<<dim3(9, HEADS, BT), 256, 0, stream>>>(x, Wt, bias, motion,
                                                          kvw, ksw, out);
}

// Round 3
// 571.131 us; speedup vs baseline: 4.0811x; 1.1932x over previous
//
#include <hip/hip_runtime.h>
#include <cstddef>
#include <cstdint>

#define HEADS 8
#define DH 64
#define C 512
#define TC 1536
#define BT 32
#define NTOK 2304
#define TT 16
#define EPS 1e-6f

typedef __attribute__((ext_vector_type(8))) short bf16x8;
typedef __attribute__((ext_vector_type(4))) float f32x4;
typedef __attribute__((address_space(3))) void as3_void;
typedef __attribute__((address_space(1))) const void as1_cvoid;

__device__ __forceinline__ float fmap(float x) {
    return x > 0.f ? x + 1.f : __expf(x);
}
__device__ __forceinline__ unsigned short f2bf(float f) {
    unsigned int u = __float_as_uint(f);
    return (unsigned short)((u + 0x7fffu + ((u >> 16) & 1u)) >> 16);
}
__device__ __forceinline__ unsigned int pack2bf(float a, float b) {
    return (unsigned int)f2bf(a) | ((unsigned int)f2bf(b) << 16);
}
__device__ __forceinline__ float bf2f(unsigned short h) {
    return __uint_as_float(((unsigned int)h) << 16);
}
// async global->LDS DMA, 16B/lane. LDS dest = wave-uniform base + lane*16.
__device__ __forceinline__ void gload16(const void* g, void* l) {
    __builtin_amdgcn_global_load_lds((as1_cvoid*)(uintptr_t)g,
                                     (as3_void*)(uintptr_t)l, 16, 0, 0);
}

// ---------------------------------------------------------------------------
// K0: Wt[col][c] (bf16) = W[c][col]. grid (48,16).
// ---------------------------------------------------------------------------
__global__ __launch_bounds__(256) void k_prep_w(
    const float* __restrict__ W, unsigned short* __restrict__ Wt) {
    __shared__ float tile[32][33];
    int col0 = blockIdx.x * 32, c0 = blockIdx.y * 32;
    int tx = threadIdx.x & 31, ty = threadIdx.x >> 5;
#pragma unroll
    for (int j = 0; j < 4; ++j) {
        int c = ty + j * 8;
        tile[c][tx] = W[(size_t)(c0 + c) * TC + col0 + tx];
    }
    __syncthreads();
#pragma unroll
    for (int j = 0; j < 4; ++j) {
        int col = ty + j * 8;
        Wt[(size_t)(col0 + col) * C + c0 + tx] = f2bf(tile[tx][col]);
    }
}

// ---------------------------------------------------------------------------
// K1: x_time channel sums + motion mean sums + stage xb = bf16(x).
// grid (BT, 8), block 256; thread <-> 2 consecutive channels.
// ---------------------------------------------------------------------------
__global__ __launch_bounds__(256) void k_time_reduce(
    const float* __restrict__ x, const float* __restrict__ motion,
    float* __restrict__ xtraw, float* __restrict__ mmraw,
    unsigned short* __restrict__ xb) {
    int bt = blockIdx.x, sp = blockIdx.y, tid = threadIdx.x;
    int n0 = sp * 288, cid = tid * 2;
    const float* xp = x + ((size_t)(bt * NTOK + n0)) * C + cid;
    unsigned short* xbp = xb + ((size_t)(bt * NTOK + n0)) * C + cid;
    float s0 = 0.f, s1 = 0.f;
    for (int n = 0; n < 288; ++n) {
        float2 v = *(const float2*)(xp + (size_t)n * C);
        s0 += v.x;
        s1 += v.y;
        *(unsigned int*)(xbp + (size_t)n * C) = pack2bf(v.x, v.y);
    }
    atomicAdd(&xtraw[bt * C + cid], s0);
    atomicAdd(&xtraw[bt * C + cid + 1], s1);

    const float* mp = motion + (size_t)bt * NTOK + n0;
    float m = mp[tid];
    if (tid < 32) m += mp[256 + tid];
    __shared__ float red[256];
    red[tid] = m;
    __syncthreads();
    for (int s = 128; s > 0; s >>= 1) {
        if (tid < s) red[tid] += red[tid + s];
        __syncthreads();
    }
    if (tid == 0) atomicAdd(&mmraw[bt], red[0]);
}

// ---------------------------------------------------------------------------
// K2a: qkv_time[bt][col] = x_time[bt] @ W.  grid (BT, 6).
// ---------------------------------------------------------------------------
__global__ __launch_bounds__(256) void k_time_qkv(
    const float* __restrict__ xtraw, const float* __restrict__ temb,
    const float* __restrict__ W, float* __restrict__ qkvt) {
    int bt = blockIdx.x, col = blockIdx.y * 256 + threadIdx.x, tid = threadIdx.x;
    __shared__ float xl[C];
    xl[tid]       = xtraw[bt * C + tid]       * (1.f / NTOK) + temb[tid];
    xl[tid + 256] = xtraw[bt * C + tid + 256] * (1.f / NTOK) + temb[tid + 256];
    __syncthreads();
    float a = 0.f;
#pragma unroll 8
    for (int c = 0; c < C; ++c) a += xl[c] * W[(size_t)c * TC + col];
    qkvt[(size_t)bt * TC + col] = a;
}

// ---------------------------------------------------------------------------
// K2b: temporal linear attention -> bias[bt][c] = temb[c] + t_out.
// ---------------------------------------------------------------------------
__global__ __launch_bounds__(256) void k_time_attn(
    const float* __restrict__ qkvt, const float* __restrict__ mmraw,
    const float* __restrict__ temb, float* __restrict__ bias) {
    int b = blockIdx.x, h = blockIdx.y, tid = threadIdx.x;
    int d = tid & 63, g = tid >> 6;
    __shared__ float qs[TT][DH], ks[TT][DH], vs[TT][DH], ksum[DH];
    __shared__ float kvl[DH][DH];
    for (int t = g; t < TT; t += 4) {
        size_t base = (size_t)(b * TT + t) * TC + h * DH + d;
        float mwt = 1.f + tanhf(mmraw[b * TT + t] * (1.f / NTOK));
        qs[t][d] = fmap(qkvt[base]) * mwt;
        ks[t][d] = fmap(qkvt[base + C]);
        vs[t][d] = qkvt[base + 2 * C];
    }
    __syncthreads();
    if (g == 0) {
        float s = 0.f;
        for (int t = 0; t < TT; ++t) s += ks[t][d];
        ksum[d] = s;
    }
    float kva[16];
#pragma unroll
    for (int i = 0; i < 16; ++i) kva[i] = 0.f;
    for (int t = 0; t < TT; ++t) {
        float kd = ks[t][d];
#pragma unroll
        for (int i = 0; i < 16; ++i) kva[i] += kd * vs[t][g * 16 + i];
    }
#pragma unroll
    for (int i = 0; i < 16; ++i) kvl[d][g * 16 + i] = kva[i];
    __syncthreads();
    for (int tt = 0; tt < 4; ++tt) {
        int t = g * 4 + tt;
        float acc = 0.f, zden = 0.f;
        for (int dd = 0; dd < DH; ++dd) {
            float qv = qs[t][dd];
            acc  += qv * kvl[dd][d];
            zden += qv * ksum[dd];
        }
        bias[(size_t)(b * TT + t) * C + h * DH + d] =
            acc / (zden + EPS) + temb[h * DH + d];
    }
}

// ---------------------------------------------------------------------------
// K2c: bvec[bt][col] = bias[bt] @ W.  grid (BT, 6).
// ---------------------------------------------------------------------------
__global__ __launch_bounds__(256) void k_bias_vec(
    const float* __restrict__ bias, const float* __restrict__ W,
    float* __restrict__ bvec) {
    int bt = blockIdx.x, col = blockIdx.y * 256 + threadIdx.x, tid = threadIdx.x;
    __shared__ float bl[C];
    bl[tid]       = bias[bt * C + tid];
    bl[tid + 256] = bias[bt * C + tid + 256];
    __syncthreads();
    float a = 0.f;
#pragma unroll 8
    for (int c = 0; c < C; ++c) a += bl[c] * W[(size_t)c * TC + col];
    bvec[(size_t)bt * TC + col] = a;
}

// ---------------------------------------------------------------------------
// K3: spatial pass A. grid (6, 4 head-pairs, BT), 512 threads (8 waves).
// Per tile (128 tok): GEMM xb@W -> k|v for 2 heads (256 cols), BK=64,
// global_load_lds DMA into XOR-swizzled LDS; epilogue: +bvec, fmap(k),
// kv += kT@v and ksum via MFMA; atomics into ws.
// ---------------------------------------------------------------------------
__global__ __launch_bounds__(512) void k_spatial_kv(
    const unsigned short* __restrict__ xb, const unsigned short* __restrict__ Wt,
    const float* __restrict__ bvec, float* __restrict__ kvw,
    float* __restrict__ ksw) {
    __shared__ __align__(16) char smem[50176];
    unsigned short* A_s = (unsigned short*)smem;            // 128 rows x 64 sh
    unsigned short* B_s = (unsigned short*)(smem + 16384);  // 256 rows x 64 sh
    char* kvT = smem;                                       // 128 rows x 256 B alias
    float* bvl = (float*)(smem + 49152);                    // 256

    const int s = blockIdx.x, hp = blockIdx.y, bt = blockIdx.z;
    const int tid = threadIdx.x, lane = tid & 63, w = tid >> 6;
    const int lm = lane & 15, quad = lane >> 4;
    const int mr = w & 1, nc = w >> 1;
    const int li8 = lane >> 3, lp = lane & 7;

    if (tid < 256) {
        int h2 = tid >> 7, j2 = tid & 127;
        int wr = (j2 < 64) ? (C + (hp * 2 + h2) * DH + j2)
                           : (2 * C + (hp * 2 + h2) * DH + (j2 - 64));
        bvl[tid] = bvec[(size_t)bt * TC + wr];
    }
    float ksp0 = 0.f, ksp1 = 0.f;
    f32x4 kvacc[2][2];
#pragma unroll
    for (int a = 0; a < 2; ++a)
#pragma unroll
        for (int b = 0; b < 2; ++b) kvacc[a][b] = (f32x4)0.f;

    for (int t = 0; t < 3; ++t) {
        const int n0 = (s * 3 + t) * 128;
        f32x4 acc[4][4];
#pragma unroll
        for (int i = 0; i < 4; ++i)
#pragma unroll
            for (int j = 0; j < 4; ++j) acc[i][j] = (f32x4)0.f;

        for (int kc = 0; kc < 8; ++kc) {
            __syncthreads();
#pragma unroll
            for (int l = 0; l < 2; ++l) {  // A: 128 rows total
                int rowbase = w * 16 + l * 8;
                int row = rowbase + li8;
                int c = lp ^ (row & 7);
                gload16(xb + ((size_t)(bt * NTOK + n0 + row)) * C + kc * 64 + c * 8,
                        A_s + rowbase * 64);
            }
#pragma unroll
            for (int l = 0; l < 4; ++l) {  // B: 256 rows total
                int rowbase = w * 32 + l * 8;
                int r = rowbase + li8;
                int c = lp ^ (r & 7);
                int h2 = r >> 7, j2 = r & 127;
                int wr = (j2 < 64) ? (C + (hp * 2 + h2) * DH + j2)
                                   : (2 * C + (hp * 2 + h2) * DH + (j2 - 64));
                gload16(Wt + (size_t)wr * C + kc * 64 + c * 8, B_s + rowbase * 64);
            }
            __syncthreads();
#pragma unroll
            for (int ks = 0; ks < 2; ++ks) {
                bf16x8 af[4], bfr[4];
#pragma unroll
                for (int i = 0; i < 4; ++i) {
                    int row = mr * 64 + i * 16 + lm;
                    int p = (ks * 4 + quad) ^ (row & 7);
                    af[i] = *(const bf16x8*)&A_s[row * 64 + p * 8];
                }
#pragma unroll
                for (int j = 0; j < 4; ++j) {
                    int row = nc * 64 + j * 16 + lm;
                    int p = (ks * 4 + quad) ^ (row & 7);
                    bfr[j] = *(const bf16x8*)&B_s[row * 64 + p * 8];
                }
#pragma unroll
                for (int i = 0; i < 4; ++i)
#pragma unroll
                    for (int j = 0; j < 4; ++j)
                        acc[i][j] = __builtin_amdgcn_mfma_f32_16x16x32_bf16(
                            af[i], bfr[j], acc[i][j], 0, 0, 0);
            }
        }
        // ---- epilogue: per head of the pair ----
#pragma unroll 1
        for (int ph = 0; ph < 2; ++ph) {
            __syncthreads();
            if ((nc >> 1) == ph) {  // waves holding this head's 128 cols write kvT
#pragma unroll
                for (int i = 0; i < 4; ++i) {
                    int tokb = mr * 64 + i * 16 + quad * 4;
                    int tc = tokb >> 3;
#pragma unroll
                    for (int j = 0; j < 4; ++j) {
                        int cg = nc * 64 + j * 16 + lm;
                        int cl = cg & 127;
                        float bv = bvl[cg];
                        f32x4 a4 = acc[i][j];
                        float v0 = a4[0] + bv, v1 = a4[1] + bv;
                        float v2 = a4[2] + bv, v3 = a4[3] + bv;
                        if (cl < 64) {
                            v0 = fmap(v0); v1 = fmap(v1);
                            v2 = fmap(v2); v3 = fmap(v3);
                        }
                        int p = (tc & 8) | ((tc & 7) ^ (cl & 7));
                        uint2 pk;
                        pk.x = pack2bf(v0, v1);
                        pk.y = pack2bf(v2, v3);
                        *(uint2*)(kvT + cl * 256 + p * 16 + (tokb & 7) * 2) = pk;
                    }
                }
            }
            __syncthreads();
            if (tid < 128) {  // ksum partials: (d, token-half)
                int d = tid & 63, half = tid >> 6;
                float ssum = 0.f;
#pragma unroll
                for (int tc2 = 0; tc2 < 8; ++tc2) {
                    int tcc = half * 8 + tc2;
                    int p = (tcc & 8) | ((tcc & 7) ^ (d & 7));
                    bf16x8 v8 = *(const bf16x8*)(kvT + d * 256 + p * 16);
#pragma unroll
                    for (int q = 0; q < 8; ++q)
                        ssum += bf2f((unsigned short)v8[q]);
                }
                if (ph == 0) ksp0 += ssum; else ksp1 += ssum;
            }
            // kv += kT @ v (K = 128 tokens); wave -> (dt pair, et)
#pragma unroll
            for (int dt2 = 0; dt2 < 2; ++dt2) {
                int drow = (mr * 2 + dt2) * 16 + lm;
                int erow = 64 + nc * 16 + lm;
#pragma unroll
                for (int ks2 = 0; ks2 < 4; ++ks2) {
                    int tcc = ks2 * 4 + quad;
                    int pA = (tcc & 8) | ((tcc & 7) ^ (drow & 7));
                    int pB = (tcc & 8) | ((tcc & 7) ^ (erow & 7));
                    bf16x8 ak = *(const bf16x8*)(kvT + drow * 256 + pA * 16);
                    bf16x8 bv8 = *(const bf16x8*)(kvT + erow * 256 + pB * 16);
                    kvacc[ph][dt2] = __builtin_amdgcn_mfma_f32_16x16x32_bf16(
                        ak, bv8, kvacc[ph][dt2], 0, 0, 0);
                }
            }
        }
    }
#pragma unroll
    for (int ph = 0; ph < 2; ++ph) {
        float* kvp = kvw + (size_t)(bt * HEADS + hp * 2 + ph) * DH * DH;
#pragma unroll
        for (int dt2 = 0; dt2 < 2; ++dt2) {
            int d0 = (mr * 2 + dt2) * 16 + quad * 4;
            int e = nc * 16 + lm;
#pragma unroll
            for (int r = 0; r < 4; ++r)
                atomicAdd(&kvp[(d0 + r) * DH + e], kvacc[ph][dt2][r]);
        }
    }
    if (tid < 128) {
        int d = tid & 63;
        atomicAdd(&ksw[(bt * HEADS + hp * 2 + 0) * DH + d], ksp0);
        atomicAdd(&ksw[(bt * HEADS + hp * 2 + 1) * DH + d], ksp1);
    }
}

// ---------------------------------------------------------------------------
// K4: spatial pass B. grid (18, 4 head-pairs, BT), 256 threads (4 waves).
// GEMM xb@Wq (128 tok x 128 cols = 2 heads), q=fmap(.+bvec)*mw -> LDS,
// out = (q@kv) * z via MFMA.
// ---------------------------------------------------------------------------
__global__ __launch_bounds__(256) void k_spatial_out(
    const unsigned short* __restrict__ xb, const unsigned short* __restrict__ Wt,
    const float* __restrict__ bvec, const float* __restrict__ motion,
    const float* __restrict__ kvw, const float* __restrict__ ksw,
    float* __restrict__ out) {
    __shared__ __align__(16) char smem[51712];
    unsigned short* A_s = (unsigned short*)smem;            // 128 x 64 sh
    unsigned short* B_s = (unsigned short*)(smem + 16384);  // 128 x 64 sh
    char* qs  = smem;                                       // 128 tok x 256 B alias
    char* kvT = smem + 32768;                               // 128 rows x 128 B
    float* bvl = (float*)(smem + 49152);                    // 128
    float* mwv = (float*)(smem + 49664);                    // 128
    float* ksl = (float*)(smem + 50176);                    // 128 (2 heads x 64)
    float* zv  = (float*)(smem + 50688);                    // 256 (2 heads x 128)

    const int tile = blockIdx.x, hp = blockIdx.y, bt = blockIdx.z;
    const int tid = threadIdx.x, lane = tid & 63, w = tid >> 6;
    const int lm = lane & 15, quad = lane >> 4;
    const int mr = w & 1, nc = w >> 1;
    const int li8 = lane >> 3, lp = lane & 7;
    const int n0 = tile * 128;

    if (tid < 128) {
        bvl[tid] = bvec[(size_t)bt * TC + hp * 128 + tid];
        mwv[tid] = 1.f + tanhf(motion[(size_t)bt * NTOK + n0 + tid]);
        ksl[tid] = ksw[(bt * HEADS + hp * 2 + (tid >> 6)) * DH + (tid & 63)];
    }
    {   // kvT[head*64+e][d] = bf16(kvw[head][d][e]), swizzled
        int rr = tid & 127, hh = tid >> 7;
        int head = rr >> 6, e = rr & 63;
        const float* kvp = kvw + (size_t)(bt * HEADS + hp * 2 + head) * DH * DH;
#pragma unroll 8
        for (int d = hh * 32; d < hh * 32 + 32; ++d) {
            int p = (d >> 3) ^ (rr & 7);
            ((unsigned short*)(kvT + rr * 128 + p * 16))[d & 7] = f2bf(kvp[d * DH + e]);
        }
    }
    f32x4 acc[4][4];
#pragma unroll
    for (int i = 0; i < 4; ++i)
#pragma unroll
        for (int j = 0; j < 4; ++j) acc[i][j] = (f32x4)0.f;

    for (int kc = 0; kc < 8; ++kc) {
        __syncthreads();
#pragma unroll
        for (int l = 0; l < 4; ++l) {
            int rowbase = w * 32 + l * 8;
            int row = rowbase + li8;
            int c = lp ^ (row & 7);
            gload16(xb + ((size_t)(bt * NTOK + n0 + row)) * C + kc * 64 + c * 8,
                    A_s + rowbase * 64);
        }
#pragma unroll
        for (int l = 0; l < 4; ++l) {
            int rowbase = w * 32 + l * 8;
            int r = rowbase + li8;
            int c = lp ^ (r & 7);
            gload16(Wt + (size_t)(hp * 128 + r) * C + kc * 64 + c * 8,
                    B_s + rowbase * 64);
        }
        __syncthreads();
#pragma unroll
        for (int ks = 0; ks < 2; ++ks) {
            bf16x8 af[4], bfr[4];
#pragma unroll
            for (int i = 0; i < 4; ++i) {
                int row = mr * 64 + i * 16 + lm;
                int p = (ks * 4 + quad) ^ (row & 7);
                af[i] = *(const bf16x8*)&A_s[row * 64 + p * 8];
            }
#pragma unroll
            for (int j = 0; j < 4; ++j) {
                int row = nc * 64 + j * 16 + lm;
                int p = (ks * 4 + quad) ^ (row & 7);
                bfr[j] = *(const bf16x8*)&B_s[row * 64 + p * 8];
            }
#pragma unroll
            for (int i = 0; i < 4; ++i)
#pragma unroll
                for (int j = 0; j < 4; ++j)
                    acc[i][j] = __builtin_amdgcn_mfma_f32_16x16x32_bf16(
                        af[i], bfr[j], acc[i][j], 0, 0, 0);
        }
    }
    __syncthreads();
    // q -> qs (bf16, swizzled [tok][col 0..127])
#pragma unroll
    for (int i = 0; i < 4; ++i) {
#pragma unroll
        for (int j = 0; j < 4; ++j) {
            int cl = nc * 64 + j * 16 + lm;
            float bv = bvl[cl];
            int cch = cl >> 3;
#pragma unroll
            for (int r = 0; r < 4; ++r) {
                int tok = mr * 64 + i * 16 + quad * 4 + r;
                float qv = fmap(acc[i][j][r] + bv) * mwv[tok];
                int p = (cch & 8) | ((cch & 7) ^ (tok & 7));
                ((unsigned short*)(qs + tok * 256 + p * 16))[cl & 7] = f2bf(qv);
            }
        }
    }
    __syncthreads();
    {   // z per (head, tok)
        int head = tid >> 7, tok = tid & 127;
        float zd = 0.f;
#pragma unroll
        for (int tc3 = 0; tc3 < 8; ++tc3) {
            int cch = head * 8 + tc3;
            int p = (cch & 8) | ((cch & 7) ^ (tok & 7));
            bf16x8 q8 = *(const bf16x8*)(qs + tok * 256 + p * 16);
#pragma unroll
            for (int q = 0; q < 8; ++q)
                zd += bf2f((unsigned short)q8[q]) * ksl[head * 64 + tc3 * 8 + q];
        }
        zv[head * 128 + tok] = 1.f / (zd + EPS);
    }
    __syncthreads();
    // out = q @ kv ; wave (mr, nc): rows mr*64.., head nc
    f32x4 oacc[4][4];
#pragma unroll
    for (int i = 0; i < 4; ++i)
#pragma unroll
        for (int j = 0; j < 4; ++j) oacc[i][j] = (f32x4)0.f;
#pragma unroll
    for (int ks3 = 0; ks3 < 2; ++ks3) {
        bf16x8 aq[4], bk[4];
#pragma unroll
        for (int i = 0; i < 4; ++i) {
            int tok = mr * 64 + i * 16 + lm;
            int cch = nc * 8 + ks3 * 4 + quad;
            int p = (cch & 8) | ((cch & 7) ^ (tok & 7));
            aq[i] = *(const bf16x8*)(qs + tok * 256 + p * 16);
        }
#pragma unroll
        for (int j = 0; j < 4; ++j) {
            int row = nc * 64 + j * 16 + lm;
            int tcc = ks3 * 4 + quad;
            int p = tcc ^ (row & 7);
            bk[j] = *(const bf16x8*)(kvT + row * 128 + p * 16);
        }
#pragma unroll
        for (int i = 0; i < 4; ++i)
#pragma unroll
            for (int j = 0; j < 4; ++j)
                oacc[i][j] = __builtin_amdgcn_mfma_f32_16x16x32_bf16(
                    aq[i], bk[j], oacc[i][j], 0, 0, 0);
    }
    const int h = hp * 2 + nc;
#pragma unroll
    for (int i = 0; i < 4; ++i)
#pragma unroll
        for (int r = 0; r < 4; ++r) {
            int tok = mr * 64 + i * 16 + quad * 4 + r;
            float z = zv[nc * 128 + tok];
#pragma unroll
            for (int j = 0; j < 4; ++j)
                out[((size_t)(bt * NTOK + n0 + tok)) * C + h * DH + j * 16 + lm] =
                    oacc[i][j][r] * z;
        }
}

// ---------------------------------------------------------------------------
extern "C" void kernel_launch(void* const* d_in, const int* in_sizes, int n_in,
                              void* d_out, int out_size, void* d_ws, size_t ws_size,
                              hipStream_t stream) {
    (void)in_sizes; (void)n_in; (void)out_size; (void)ws_size;
    const float* x      = (const float*)d_in[0];
    const float* motion = (const float*)d_in[1];
    const float* W      = (const float*)d_in[2];
    const float* temb   = (const float*)d_in[3];
    float* out = (float*)d_out;
    float* ws  = (float*)d_ws;

    // ws layout (float offsets)
    float* kvw   = ws;                     // 1048576
    float* ksw   = kvw + 1048576;          // 16384
    float* xtraw = ksw + 16384;            // 16384
    float* mmraw = xtraw + 16384;          // 32
    float* qkvt  = mmraw + 32;             // 49152
    float* bias  = qkvt + 49152;           // 16384
    float* bvec  = bias + 16384;           // 49152
    unsigned short* Wt = (unsigned short*)(bvec + 49152);  // 1536*512 bf16
    unsigned short* xb = (unsigned short*)(Wt + (size_t)TC * C);  // 73728*512 bf16

    hipMemsetAsync(d_ws, 0,
                   (size_t)(1048576 + 16384 + 16384 + 32) * sizeof(float), stream);
    k_prep_w<<<dim3(48, 16), 256, 0, stream>>>(W, Wt);
    k_time_reduce<<<dim3(BT, 8), 256, 0, stream>>>(x, motion, xtraw, mmraw, xb);
    k_time_qkv<<<dim3(BT, 6), 256, 0, stream>>>(xtraw, temb, W, qkvt);
    k_time_attn<<<dim3(2, HEADS), 256, 0, stream>>>(qkvt, mmraw, temb, bias);
    k_bias_vec<<<dim3(BT, 6), 256, 0, stream>>>(bias, W, bvec);
    k_spatial_kv<<<dim3(6, 4, BT), 512, 0, stream>>>(xb, Wt, bvec, kvw, ksw);
    k_spatial_out<<<dim3(18, 4, BT), 256, 0, stream>>>(xb, Wt, bvec, motion,
                                                       kvw, ksw, out);
}